// Round 12
// baseline (821.157 us; speedup 1.0000x reference)
//
#include <hip/hip_runtime.h>
#include <hip/hip_bf16.h>
#include <math.h>

// ---------------------------------------------------------------------------
// BayerKP demosaic KPN. R12: R10 (435us champion, exact) + one-row software
// pipeline: MFMA(row J) -> accCur while softmax-epilogue(row J-1) runs on
// accPrev (no dependence -> VALU hides under MFMA shadow). Two named acc
// sets, 2x-unrolled loop, all-static indexing. exp -> exp2 via log2(e)
// folded into W4/b4 at repack.
// ---------------------------------------------------------------------------

typedef __attribute__((ext_vector_type(8))) short short8;
typedef __attribute__((ext_vector_type(4))) short short4v;
typedef __attribute__((ext_vector_type(4))) float f32x4;

static __device__ __forceinline__ short f2bf(float v) {
    __bf16 h = (__bf16)v;
    return __builtin_bit_cast(short, h);
}

__global__ __launch_bounds__(256) void split_k(const float* __restrict__ mosaic,
                                               float* __restrict__ x0) {
    int idx = blockIdx.x * 256 + threadIdx.x;
    const int total = 2 * 4 * 384 * 384;
    if (idx >= total) return;
    int x = idx % 384;
    int t = idx / 384;
    int y = t % 384;  t /= 384;
    int c = t % 4;
    int b = t / 4;
    int Y = 2 * y + ((c == 1 || c == 3) ? 1 : 0);
    int X = 2 * x + ((c == 2 || c == 3) ? 1 : 0);
    const float* mb = mosaic + (size_t)b * 3 * 768 * 768;
    float g = mb[Y * 768 + X] + mb[768 * 768 + Y * 768 + X] + mb[2 * 768 * 768 + Y * 768 + X];
    x0[idx] = g;
}

// repack W[64][64][3][3] f32 -> Wq[9][64][64] bf16 (conv1-3)
__global__ __launch_bounds__(256) void repack_k(const float* __restrict__ W,
                                                short* __restrict__ dst) {
    int idx = blockIdx.x * 256 + threadIdx.x;
    if (idx >= 9 * 64 * 64) return;
    int ic = idx % 64;
    int t2 = idx / 64;
    int oc = t2 % 64;
    int t  = t2 / 64;
    dst[idx] = f2bf(W[((size_t)oc * 64 + ic) * 9 + t]);
}

// conv4 repack, permuted + scaled by log2(e) (softmax uses exp2 directly):
// group k = ocn/64 (10 groups), slot ql = ocn%64, orig ch = 49*k+ql (ql<49).
__global__ __launch_bounds__(256) void repack4_k(const float* __restrict__ W4,
                                                 const float* __restrict__ b4,
                                                 short* __restrict__ Wq,
                                                 float* __restrict__ bq) {
    const float LOG2E = 1.44269504088896340736f;
    int idx = blockIdx.x * 256 + threadIdx.x;
    if (idx < 9 * 640 * 64) {
        int ic  = idx % 64;
        int t2  = idx / 64;
        int ocn = t2 % 640;
        int tap = t2 / 640;
        int k  = ocn >> 6;
        int ql = ocn & 63;
        float v = (ql < 49) ? W4[((size_t)(49 * k + ql) * 64 + ic) * 9 + tap] * LOG2E : 0.f;
        Wq[idx] = f2bf(v);
    }
    if (idx < 640) {
        int k = idx >> 6, ql = idx & 63;
        bq[idx] = (ql < 49) ? b4[49 * k + ql] * LOG2E : 0.f;
    }
}

// conv0: direct f32, Cin=4, 384->382, ReLU, NHWC bf16 out
__global__ __launch_bounds__(256) void conv0_k(const float* __restrict__ x0f,
                                               const float* __restrict__ W0,
                                               const float* __restrict__ b0,
                                               short* __restrict__ out) {
    __shared__ float w[64 * 36];
    __shared__ float bb[64];
    for (int e = threadIdx.x; e < 64 * 36; e += 256) w[e] = W0[e];
    if (threadIdx.x < 64) bb[threadIdx.x] = b0[threadIdx.x];
    __syncthreads();
    int idx = blockIdx.x * 256 + threadIdx.x;
    if (idx >= 2 * 382 * 382) return;
    int x = idx % 382;
    int t = idx / 382;
    int y = t % 382;
    int b = t / 382;
    const float* base = x0f + (size_t)b * 4 * 384 * 384;
    float in[4][9];
#pragma unroll
    for (int ic = 0; ic < 4; ++ic)
#pragma unroll
        for (int ky = 0; ky < 3; ++ky)
#pragma unroll
            for (int kx = 0; kx < 3; ++kx)
                in[ic][ky * 3 + kx] = base[ic * 384 * 384 + (y + ky) * 384 + (x + kx)];
    short* op = out + (((size_t)b * 382 + y) * 382 + x) * 64;
    float accs[8];
    for (int og = 0; og < 8; ++og) {
#pragma unroll
        for (int oo = 0; oo < 8; ++oo) {
            int oc = og * 8 + oo;
            float acc = bb[oc];
            const float* wp = w + oc * 36;
#pragma unroll
            for (int ic = 0; ic < 4; ++ic)
#pragma unroll
                for (int e = 0; e < 9; ++e)
                    acc = fmaf(in[ic][e], wp[ic * 9 + e], acc);
            accs[oo] = fmaxf(acc, 0.f);
        }
        short8 pk;
#pragma unroll
        for (int oo = 0; oo < 8; ++oo) pk[oo] = f2bf(accs[oo]);
        *(short8*)(op + og * 8) = pk;
    }
}

// Persistent-weight conv, counted-vmcnt row pipeline + one-row-deferred
// epilogue. EPI=0: bias+ReLU+bf16 NHWC store. EPI=1: conv4 softmax groups.
template <int EPI>
__global__ __launch_bounds__(256, 2) void convp_k(
    const short* __restrict__ act,   // NHWC bf16 [2][Hin][Hin][64]
    int Hin, int Hout, int YITER, int nstrips,
    const short* __restrict__ Wq,    // [9][CoutT][64] bf16
    int CoutT,
    const float* __restrict__ bias,
    short* __restrict__ outbf,       // EPI=0
    const float* __restrict__ x0f,   // EPI=1
    float* __restrict__ out,         // EPI=1
    float* __restrict__ pM, float* __restrict__ pD, float* __restrict__ pN) {
    const int tid = threadIdx.x;
    const int wave = tid >> 6;
    const int lane = tid & 63;
    const int wr = wave >> 1, wc = wave & 1;
    const int l15 = lane & 15, l4 = lane >> 4;

    // bijective XCD swizzle (grid % 8 == 0); z,xt fastest for L2 act reuse
    const int q8 = gridDim.x >> 3;
    int L = ((int)blockIdx.x & 7) * q8 + ((int)blockIdx.x >> 3);
    int z = 0;
    if (EPI) { z = L % 10; L /= 10; }
    const int xt = L % 6; L /= 6;
    const int strip = L % nstrips;
    const int b = L / nstrips;
    const int x0c = xt * 64;
    const int y0 = strip * YITER;
    const int cnt = min(YITER, Hout - y0);
    if (cnt <= 0) return;

    __shared__ __align__(16) short Bt[8 * 528 * 8];  // 8-slot row ring
    __shared__ float smM[2][64], smD[2][64], smN[2][64];
    __shared__ float smP[17 * 72];                    // EPI plane window, f32

    auto stage_row = [&](int r) {
        const size_t rowbase = ((size_t)b * Hin + r) * (size_t)Hin;
        const int ring = (r & 7) * 528;
#pragma unroll
        for (int i = 0; i < 2; ++i) {
            int s = i * 256 + tid;
            int xl = s >> 3, sl = s & 7;
            int gx = x0c + xl; if (gx > Hin - 1) gx = Hin - 1;
            const short* src = act + (rowbase + gx) * 64 + ((sl ^ (xl & 7)) << 3);
            __builtin_amdgcn_global_load_lds(
                (const __attribute__((address_space(1))) void*)src,
                (__attribute__((address_space(3))) void*)((char*)Bt + (ring + s) * 16),
                16, 0, 0);
        }
        if (tid < 16) {
            int s = 512 + tid;
            int xl = s >> 3, sl = s & 7;
            int gx = x0c + xl; if (gx > Hin - 1) gx = Hin - 1;
            const short* src = act + (rowbase + gx) * 64 + ((sl ^ (xl & 7)) << 3);
            __builtin_amdgcn_global_load_lds(
                (const __attribute__((address_space(1))) void*)src,
                (__attribute__((address_space(3))) void*)((char*)Bt + (ring + s) * 16),
                16, 0, 0);
        }
    };

    // --- persistent weight fragments: 36 short8 per wave ---
    const int zrow = EPI ? z * 64 : 0;
    short8 wreg[9][2][2];
#pragma unroll
    for (int tap = 0; tap < 9; ++tap)
#pragma unroll
        for (int kk = 0; kk < 2; ++kk)
#pragma unroll
            for (int m = 0; m < 2; ++m)
                wreg[tap][kk][m] = *(const short8*)(Wq +
                    ((size_t)tap * CoutT + zrow + wr * 32 + m * 16 + l15) * 64
                    + kk * 32 + l4 * 8);

    // --- EPI loop-invariant precompute + LDS plane window ---
    float bv[2][4];
    int goff[2][4];
    if (EPI) {
        int pidx = (z < 3) ? 2 : (z < 6) ? 1 : ((z & 1) ? 3 : 0);
        const float* plane = x0f + ((size_t)b * 4 + pidx) * 384 * 384;
#pragma unroll
        for (int m = 0; m < 2; ++m)
#pragma unroll
            for (int r = 0; r < 4; ++r) {
                int q = wr * 32 + m * 16 + l4 * 4 + r;
                bv[m][r] = (q < 49) ? bias[z * 64 + q] : -1e30f;
                int qc = (q < 49) ? q : 48;
                goff[m][r] = (qc / 7) * 72 + (qc % 7);
            }
        for (int e = tid; e < 17 * 70; e += 256) {
            int pr = e / 70, pc = e % 70;
            int gy = y0 + 2 + pr; if (gy > 383) gy = 383;
            int gx = x0c + 2 + pc; if (gx > 383) gx = 383;
            smP[pr * 72 + pc] = plane[gy * 384 + gx];
        }
    }

// --- epilogue of one completed row (macro: named acc, static indexing) ---
#define FLUSH_ROW(OROW, ISTR, AC)                                             \
    do {                                                                      \
        const int orow_ = (OROW);                                             \
        if (!EPI) {                                                           \
            _Pragma("unroll")                                                 \
            for (int m = 0; m < 2; ++m) {                                     \
                int ocb = wr * 32 + m * 16 + l4 * 4;                          \
                _Pragma("unroll")                                             \
                for (int n = 0; n < 2; ++n) {                                 \
                    int x = x0c + wc * 32 + n * 16 + l15;                     \
                    if (x >= Hout) continue;                                  \
                    size_t off = (((size_t)b * Hout + orow_) * Hout + x) * 64 + ocb; \
                    short4v pk;                                               \
                    _Pragma("unroll")                                         \
                    for (int r = 0; r < 4; ++r)                               \
                        pk[r] = f2bf(fmaxf(AC[m][n][r] + bias[ocb + r], 0.f)); \
                    *(short4v*)(outbf + off) = pk;                            \
                }                                                             \
            }                                                                 \
        } else {                                                              \
            _Pragma("unroll")                                                 \
            for (int n = 0; n < 2; ++n) {                                     \
                const int xn = x0c + wc * 32 + n * 16 + l15;                  \
                const int xg = (xn < 374) ? xn : 373;                         \
                const int gbase = (ISTR) * 72 + (xg - x0c);                   \
                float mx = -1e30f;                                            \
                _Pragma("unroll")                                             \
                for (int m = 0; m < 2; ++m)                                   \
                    _Pragma("unroll")                                         \
                    for (int r = 0; r < 4; ++r)                               \
                        mx = fmaxf(mx, AC[m][n][r] + bv[m][r]);               \
                mx = fmaxf(mx, __shfl_xor(mx, 16));                           \
                mx = fmaxf(mx, __shfl_xor(mx, 32));                           \
                float den = 0.f, num = 0.f;                                   \
                _Pragma("unroll")                                             \
                for (int m = 0; m < 2; ++m)                                   \
                    _Pragma("unroll")                                         \
                    for (int r = 0; r < 4; ++r) {                             \
                        float e = exp2f(AC[m][n][r] + bv[m][r] - mx);         \
                        den += e;                                             \
                        num = fmaf(e, smP[gbase + goff[m][r]], num);          \
                    }                                                         \
                den += __shfl_xor(den, 16);  den += __shfl_xor(den, 32);      \
                num += __shfl_xor(num, 16);  num += __shfl_xor(num, 32);      \
                if (l4 == 0) {                                                \
                    int p = wc * 32 + n * 16 + l15;                           \
                    smM[wr][p] = mx;                                          \
                    smD[wr][p] = den;                                         \
                    smN[wr][p] = num;                                         \
                }                                                             \
            }                                                                 \
            asm volatile("s_waitcnt lgkmcnt(0)\n\ts_barrier" ::: "memory");   \
            if (tid < 64) {                                                   \
                int p = tid, x = x0c + p;                                     \
                if (x < 374) {                                                \
                    float m0 = smM[0][p], m1 = smM[1][p];                     \
                    float M = fmaxf(m0, m1);                                  \
                    float s0 = exp2f(m0 - M), s1 = exp2f(m1 - M);             \
                    float D = smD[0][p] * s0 + smD[1][p] * s1;                \
                    float N = smN[0][p] * s0 + smN[1][p] * s1;                \
                    if (z < 6) {                                              \
                        int color = (z < 3) ? 0 : 2;                          \
                        int oy, ox;                                           \
                        switch (z) {                                          \
                            case 0: oy = 0; ox = 0; break;                    \
                            case 1: oy = 1; ox = 0; break;                    \
                            case 2: oy = 1; ox = 1; break;                    \
                            case 3: oy = 0; ox = 0; break;                    \
                            case 4: oy = 0; ox = 1; break;                    \
                            default: oy = 1; ox = 1; break;                   \
                        }                                                     \
                        out[(((size_t)b * 3 + color) * 748 + 2 * orow_ + oy) * 748 + 2 * x + ox] = N / D; \
                    } else {                                                  \
                        size_t po = (((size_t)(z - 6) * 2 + b) * 374 + orow_) * 374 + x; \
                        pM[po] = M; pD[po] = D; pN[po] = N;                   \
                    }                                                         \
                }                                                             \
            }                                                                 \
        }                                                                     \
    } while (0)

// One pipeline step: MFMA(row y0+J) -> ACC, then epilogue(row y0+J-1) on ACCP
// (independent of this row's MFMAs -> scheduler hides the VALU under them).
#define PIPE_ITER(J, ACC, ACCP)                                               \
    if ((J) < cnt) {                                                          \
        const int j_ = (J);                                                   \
        const int y_ = y0 + j_;                                               \
        _Pragma("unroll")                                                     \
        for (int m = 0; m < 2; ++m)                                           \
            _Pragma("unroll")                                                 \
            for (int n = 0; n < 2; ++n)                                       \
                ACC[m][n] = (f32x4){0.f, 0.f, 0.f, 0.f};                      \
        _Pragma("unroll")                                                     \
        for (int tap = 0; tap < 9; ++tap) {                                   \
            const int ky = tap / 3, kx = tap % 3;                             \
            const int rbase = ((y_ + ky) & 7) * 528;                          \
            short8 bf[2][2];                                                  \
            _Pragma("unroll")                                                 \
            for (int kk = 0; kk < 2; ++kk)                                    \
                _Pragma("unroll")                                             \
                for (int n = 0; n < 2; ++n) {                                 \
                    int xl = wc * 32 + n * 16 + l15 + kx;                     \
                    int slot = (kk * 4 + l4) ^ (xl & 7);                      \
                    bf[kk][n] = *(const short8*)&Bt[(rbase + xl * 8 + slot) * 8]; \
                }                                                             \
            _Pragma("unroll")                                                 \
            for (int kk = 0; kk < 2; ++kk)                                    \
                _Pragma("unroll")                                             \
                for (int m = 0; m < 2; ++m)                                   \
                    _Pragma("unroll")                                         \
                    for (int n = 0; n < 2; ++n)                               \
                        ACC[m][n] = __builtin_amdgcn_mfma_f32_16x16x32_bf16(  \
                            wreg[tap][kk][m], bf[kk][n], ACC[m][n], 0, 0, 0); \
        }                                                                     \
        if (j_ >= 1) { FLUSH_ROW(y_ - 1, j_ - 1, ACCP); }                     \
        if (j_ <= cnt - 4) stage_row(y_ + 5);                                 \
        asm volatile("s_waitcnt vmcnt(4) lgkmcnt(0)\n\ts_barrier" ::: "memory"); \
    }

    f32x4 accA[2][2], accB[2][2];

    // prologue: stage rows y0..y0+4 (5-deep prefetch)
    stage_row(y0);
    stage_row(y0 + 1);
    stage_row(y0 + 2);
    stage_row(y0 + 3);
    stage_row(y0 + 4);
    asm volatile("s_waitcnt vmcnt(4) lgkmcnt(0)\n\ts_barrier" ::: "memory");

    for (int j = 0; j < cnt; j += 2) {
        PIPE_ITER(j, accA, accB)
        PIPE_ITER(j + 1, accB, accA)
    }
    // drain: epilogue of the last computed row
    if ((cnt - 1) & 1) { FLUSH_ROW(y0 + cnt - 1, cnt - 1, accB); }
    else               { FLUSH_ROW(y0 + cnt - 1, cnt - 1, accA); }
#undef PIPE_ITER
#undef FLUSH_ROW
}

// green partial combine + raw passthrough pixels (pM in log2 domain)
__global__ __launch_bounds__(256) void rawcomb_k(
    const float* __restrict__ x0f,
    const float* __restrict__ pM, const float* __restrict__ pD,
    const float* __restrict__ pN,
    float* __restrict__ out) {
    int idx = blockIdx.x * 256 + threadIdx.x;
    if (idx >= 2 * 374 * 374) return;
    int x = idx % 374;
    int t = idx / 374;
    int y = t % 374;
    int b = t / 374;
    const float* pb = x0f + (size_t)b * 4 * 384 * 384;
    float* ob = out + (size_t)b * 3 * 748 * 748;
    float g0v = pb[(y + 5) * 384 + x + 5];
    float blv = pb[384 * 384 + (y + 5) * 384 + x + 5];
    float rrv = pb[2 * 384 * 384 + (y + 5) * 384 + x + 5];
    float g1v = pb[3 * 384 * 384 + (y + 5) * 384 + x + 5];
    ob[((size_t)0 * 748 + 2 * y) * 748 + 2 * x + 1]     = rrv;
    ob[((size_t)2 * 748 + 2 * y + 1) * 748 + 2 * x]     = blv;
    ob[((size_t)1 * 748 + 2 * y) * 748 + 2 * x]         = g0v;
    ob[((size_t)1 * 748 + 2 * y + 1) * 748 + 2 * x + 1] = g1v;
#pragma unroll
    for (int g = 0; g < 2; ++g) {
        size_t o0 = (((size_t)(g * 2 + 0) * 2 + b) * 374 + y) * 374 + x;
        size_t o1 = (((size_t)(g * 2 + 1) * 2 + b) * 374 + y) * 374 + x;
        float m0 = pM[o0], m1 = pM[o1];
        float M = fmaxf(m0, m1);
        float s0 = exp2f(m0 - M), s1 = exp2f(m1 - M);
        float val = (pN[o0] * s0 + pN[o1] * s1) / (pD[o0] * s0 + pD[o1] * s1);
        int oy = g ? 1 : 0, ox = g ? 0 : 1;
        ob[((size_t)1 * 748 + 2 * y + oy) * 748 + 2 * x + ox] = val;
    }
}

extern "C" void kernel_launch(void* const* d_in, const int* in_sizes, int n_in,
                              void* d_out, int out_size, void* d_ws, size_t ws_size,
                              hipStream_t stream) {
    const float* mosaic = (const float*)d_in[0];
    const float* W0 = (const float*)d_in[1];  const float* b0 = (const float*)d_in[2];
    const float* W1 = (const float*)d_in[3];  const float* b1 = (const float*)d_in[4];
    const float* W2 = (const float*)d_in[5];  const float* b2 = (const float*)d_in[6];
    const float* W3 = (const float*)d_in[7];  const float* b3 = (const float*)d_in[8];
    const float* W4 = (const float*)d_in[9];  const float* b4 = (const float*)d_in[10];
    float* out = (float*)d_out;

    char* ws = (char*)d_ws;
    float* x0f    = (float*)ws;  ws += 4718592;
    short* Wq1    = (short*)ws;  ws += 73728;
    short* Wq2    = (short*)ws;  ws += 73728;
    short* Wq3    = (short*)ws;  ws += 73728;
    short* Wq4p   = (short*)ws;  ws += 737280;
    float* bias4p = (float*)ws;  ws += 2560;
    short* bufA   = (short*)ws;  ws += 37356544;
    short* bufB   = (short*)ws;  ws += 36966400;
    float* pM     = (float*)ws;  ws += 4477568;
    float* pD     = (float*)ws;  ws += 4477568;
    float* pN     = (float*)ws;

    split_k<<<(2 * 4 * 384 * 384 + 255) / 256, 256, 0, stream>>>(mosaic, x0f);

    repack_k<<<(9 * 64 * 64 + 255) / 256, 256, 0, stream>>>(W1, Wq1);
    repack_k<<<(9 * 64 * 64 + 255) / 256, 256, 0, stream>>>(W2, Wq2);
    repack_k<<<(9 * 64 * 64 + 255) / 256, 256, 0, stream>>>(W3, Wq3);
    repack4_k<<<(9 * 640 * 64 + 255) / 256, 256, 0, stream>>>(W4, b4, Wq4p, bias4p);

    conv0_k<<<(2 * 382 * 382 + 255) / 256, 256, 0, stream>>>(x0f, W0, b0, bufA);

    // conv1-3: YITER=10, 38 strips, grid 38*6*2 = 456 (%8==0)
    convp_k<0><<<456, 256, 0, stream>>>(bufA, 382, 380, 10, 38, Wq1, 64, b1,
                                        bufB, nullptr, nullptr, nullptr, nullptr, nullptr);
    convp_k<0><<<456, 256, 0, stream>>>(bufB, 380, 378, 10, 38, Wq2, 64, b2,
                                        bufA, nullptr, nullptr, nullptr, nullptr, nullptr);
    convp_k<0><<<456, 256, 0, stream>>>(bufA, 378, 376, 10, 38, Wq3, 64, b3,
                                        bufB, nullptr, nullptr, nullptr, nullptr, nullptr);

    // conv4 + epilogue: YITER=11, 34 strips, grid 10*6*34*2 = 4080 (%8==0)
    convp_k<1><<<4080, 256, 0, stream>>>(bufB, 376, 374, 11, 34, Wq4p, 640, bias4p,
                                         nullptr, x0f, out, pM, pD, pN);

    rawcomb_k<<<(2 * 374 * 374 + 255) / 256, 256, 0, stream>>>(x0f, pM, pD, pN, out);
}

// Round 13
// 473.271 us; speedup vs baseline: 1.7351x; 1.7351x over previous
//
#include <hip/hip_runtime.h>
#include <hip/hip_bf16.h>
#include <math.h>

// ---------------------------------------------------------------------------
// BayerKP demosaic KPN. R13: R10 champion (435us) consolidated.
//   - conv4 kernel EXACTLY R10's (97% of its ds_read_b128 throughput wall):
//     8-slot ring, 5-deep prefetch, counted s_waitcnt vmcnt(4) + s_barrier,
//     LDS plane window for gathers, lgkm-only mid barrier.
//   - conv1-3: YITER 5 (grid 912 = 1.8 blocks/CU, was 456 = half CUs idle).
//   - log2(e) folded into W4/b4 -> softmax uses native exp2f (R12-verified).
//   Lesson bank: >128 VGPR live state spills (R6,R12); compiler pins 128
//   (R7-R9); 3-blocks/CU LDS squeeze fails (R11). Don't revisit.
// ---------------------------------------------------------------------------

typedef __attribute__((ext_vector_type(8))) short short8;
typedef __attribute__((ext_vector_type(4))) short short4v;
typedef __attribute__((ext_vector_type(4))) float f32x4;

static __device__ __forceinline__ short f2bf(float v) {
    __bf16 h = (__bf16)v;
    return __builtin_bit_cast(short, h);
}

__global__ __launch_bounds__(256) void split_k(const float* __restrict__ mosaic,
                                               float* __restrict__ x0) {
    int idx = blockIdx.x * 256 + threadIdx.x;
    const int total = 2 * 4 * 384 * 384;
    if (idx >= total) return;
    int x = idx % 384;
    int t = idx / 384;
    int y = t % 384;  t /= 384;
    int c = t % 4;
    int b = t / 4;
    int Y = 2 * y + ((c == 1 || c == 3) ? 1 : 0);
    int X = 2 * x + ((c == 2 || c == 3) ? 1 : 0);
    const float* mb = mosaic + (size_t)b * 3 * 768 * 768;
    float g = mb[Y * 768 + X] + mb[768 * 768 + Y * 768 + X] + mb[2 * 768 * 768 + Y * 768 + X];
    x0[idx] = g;
}

// repack W[64][64][3][3] f32 -> Wq[9][64][64] bf16 (conv1-3)
__global__ __launch_bounds__(256) void repack_k(const float* __restrict__ W,
                                                short* __restrict__ dst) {
    int idx = blockIdx.x * 256 + threadIdx.x;
    if (idx >= 9 * 64 * 64) return;
    int ic = idx % 64;
    int t2 = idx / 64;
    int oc = t2 % 64;
    int t  = t2 / 64;
    dst[idx] = f2bf(W[((size_t)oc * 64 + ic) * 9 + t]);
}

// conv4 repack, permuted + scaled by log2(e) (softmax uses exp2 directly):
// group k = ocn/64 (10 groups), slot ql = ocn%64, orig ch = 49*k+ql (ql<49).
__global__ __launch_bounds__(256) void repack4_k(const float* __restrict__ W4,
                                                 const float* __restrict__ b4,
                                                 short* __restrict__ Wq,
                                                 float* __restrict__ bq) {
    const float LOG2E = 1.44269504088896340736f;
    int idx = blockIdx.x * 256 + threadIdx.x;
    if (idx < 9 * 640 * 64) {
        int ic  = idx % 64;
        int t2  = idx / 64;
        int ocn = t2 % 640;
        int tap = t2 / 640;
        int k  = ocn >> 6;
        int ql = ocn & 63;
        float v = (ql < 49) ? W4[((size_t)(49 * k + ql) * 64 + ic) * 9 + tap] * LOG2E : 0.f;
        Wq[idx] = f2bf(v);
    }
    if (idx < 640) {
        int k = idx >> 6, ql = idx & 63;
        bq[idx] = (ql < 49) ? b4[49 * k + ql] * LOG2E : 0.f;
    }
}

// conv0: direct f32, Cin=4, 384->382, ReLU, NHWC bf16 out
__global__ __launch_bounds__(256) void conv0_k(const float* __restrict__ x0f,
                                               const float* __restrict__ W0,
                                               const float* __restrict__ b0,
                                               short* __restrict__ out) {
    __shared__ float w[64 * 36];
    __shared__ float bb[64];
    for (int e = threadIdx.x; e < 64 * 36; e += 256) w[e] = W0[e];
    if (threadIdx.x < 64) bb[threadIdx.x] = b0[threadIdx.x];
    __syncthreads();
    int idx = blockIdx.x * 256 + threadIdx.x;
    if (idx >= 2 * 382 * 382) return;
    int x = idx % 382;
    int t = idx / 382;
    int y = t % 382;
    int b = t / 382;
    const float* base = x0f + (size_t)b * 4 * 384 * 384;
    float in[4][9];
#pragma unroll
    for (int ic = 0; ic < 4; ++ic)
#pragma unroll
        for (int ky = 0; ky < 3; ++ky)
#pragma unroll
            for (int kx = 0; kx < 3; ++kx)
                in[ic][ky * 3 + kx] = base[ic * 384 * 384 + (y + ky) * 384 + (x + kx)];
    short* op = out + (((size_t)b * 382 + y) * 382 + x) * 64;
    float accs[8];
    for (int og = 0; og < 8; ++og) {
#pragma unroll
        for (int oo = 0; oo < 8; ++oo) {
            int oc = og * 8 + oo;
            float acc = bb[oc];
            const float* wp = w + oc * 36;
#pragma unroll
            for (int ic = 0; ic < 4; ++ic)
#pragma unroll
                for (int e = 0; e < 9; ++e)
                    acc = fmaf(in[ic][e], wp[ic * 9 + e], acc);
            accs[oo] = fmaxf(acc, 0.f);
        }
        short8 pk;
#pragma unroll
        for (int oo = 0; oo < 8; ++oo) pk[oo] = f2bf(accs[oo]);
        *(short8*)(op + og * 8) = pk;
    }
}

// Persistent-weight conv, counted-vmcnt row pipeline (R10 structure).
// EPI=0: bias+ReLU+bf16 NHWC store. EPI=1: conv4 softmax groups.
template <int EPI>
__global__ __launch_bounds__(256, 2) void convp_k(
    const short* __restrict__ act,   // NHWC bf16 [2][Hin][Hin][64]
    int Hin, int Hout, int YITER, int nstrips,
    const short* __restrict__ Wq,    // [9][CoutT][64] bf16
    int CoutT,
    const float* __restrict__ bias,
    short* __restrict__ outbf,       // EPI=0
    const float* __restrict__ x0f,   // EPI=1
    float* __restrict__ out,         // EPI=1
    float* __restrict__ pM, float* __restrict__ pD, float* __restrict__ pN) {
    const int tid = threadIdx.x;
    const int wave = tid >> 6;
    const int lane = tid & 63;
    const int wr = wave >> 1, wc = wave & 1;
    const int l15 = lane & 15, l4 = lane >> 4;

    // bijective XCD swizzle (grid % 8 == 0); z,xt fastest for L2 act reuse
    const int q8 = gridDim.x >> 3;
    int L = ((int)blockIdx.x & 7) * q8 + ((int)blockIdx.x >> 3);
    int z = 0;
    if (EPI) { z = L % 10; L /= 10; }
    const int xt = L % 6; L /= 6;
    const int strip = L % nstrips;
    const int b = L / nstrips;
    const int x0c = xt * 64;
    const int y0 = strip * YITER;
    const int cnt = min(YITER, Hout - y0);
    if (cnt <= 0) return;

    __shared__ __align__(16) short Bt[8 * 528 * 8];  // 8-slot row ring
    __shared__ float smM[2][64], smD[2][64], smN[2][64];
    __shared__ float smP[17 * 72];                    // EPI plane window, f32

    auto stage_row = [&](int r) {
        const size_t rowbase = ((size_t)b * Hin + r) * (size_t)Hin;
        const int ring = (r & 7) * 528;
#pragma unroll
        for (int i = 0; i < 2; ++i) {
            int s = i * 256 + tid;
            int xl = s >> 3, sl = s & 7;
            int gx = x0c + xl; if (gx > Hin - 1) gx = Hin - 1;
            const short* src = act + (rowbase + gx) * 64 + ((sl ^ (xl & 7)) << 3);
            __builtin_amdgcn_global_load_lds(
                (const __attribute__((address_space(1))) void*)src,
                (__attribute__((address_space(3))) void*)((char*)Bt + (ring + s) * 16),
                16, 0, 0);
        }
        if (tid < 16) {
            int s = 512 + tid;
            int xl = s >> 3, sl = s & 7;
            int gx = x0c + xl; if (gx > Hin - 1) gx = Hin - 1;
            const short* src = act + (rowbase + gx) * 64 + ((sl ^ (xl & 7)) << 3);
            __builtin_amdgcn_global_load_lds(
                (const __attribute__((address_space(1))) void*)src,
                (__attribute__((address_space(3))) void*)((char*)Bt + (ring + s) * 16),
                16, 0, 0);
        }
    };

    // --- persistent weight fragments: 36 short8 per wave ---
    const int zrow = EPI ? z * 64 : 0;
    short8 wreg[9][2][2];
#pragma unroll
    for (int tap = 0; tap < 9; ++tap)
#pragma unroll
        for (int kk = 0; kk < 2; ++kk)
#pragma unroll
            for (int m = 0; m < 2; ++m)
                wreg[tap][kk][m] = *(const short8*)(Wq +
                    ((size_t)tap * CoutT + zrow + wr * 32 + m * 16 + l15) * 64
                    + kk * 32 + l4 * 8);

    // --- EPI loop-invariant precompute + LDS plane window ---
    float bv[2][4];
    int goff[2][4];
    if (EPI) {
        int pidx = (z < 3) ? 2 : (z < 6) ? 1 : ((z & 1) ? 3 : 0);
        const float* plane = x0f + ((size_t)b * 4 + pidx) * 384 * 384;
#pragma unroll
        for (int m = 0; m < 2; ++m)
#pragma unroll
            for (int r = 0; r < 4; ++r) {
                int q = wr * 32 + m * 16 + l4 * 4 + r;
                bv[m][r] = (q < 49) ? bias[z * 64 + q] : -1e30f;
                int qc = (q < 49) ? q : 48;
                goff[m][r] = (qc / 7) * 72 + (qc % 7);
            }
        // plane window rows [y0+2, y0+18], cols [x0c+2, x0c+71] (clamped)
        for (int e = tid; e < 17 * 70; e += 256) {
            int pr = e / 70, pc = e % 70;
            int gy = y0 + 2 + pr; if (gy > 383) gy = 383;
            int gx = x0c + 2 + pc; if (gx > 383) gx = 383;
            smP[pr * 72 + pc] = plane[gy * 384 + gx];
        }
    }

    // prologue: stage rows y0..y0+4 (5-deep prefetch)
    stage_row(y0);
    stage_row(y0 + 1);
    stage_row(y0 + 2);
    stage_row(y0 + 3);
    stage_row(y0 + 4);
    asm volatile("s_waitcnt vmcnt(4) lgkmcnt(0)\n\ts_barrier" ::: "memory");

    for (int i = 0; i < cnt; ++i) {
        const int y = y0 + i;

        f32x4 acc[2][2] = {};
#pragma unroll
        for (int tap = 0; tap < 9; ++tap) {
            const int ky = tap / 3, kx = tap % 3;
            const int rbase = ((y + ky) & 7) * 528;
            short8 bf[2][2];
#pragma unroll
            for (int kk = 0; kk < 2; ++kk)
#pragma unroll
                for (int n = 0; n < 2; ++n) {
                    int xl = wc * 32 + n * 16 + l15 + kx;
                    int slot = (kk * 4 + l4) ^ (xl & 7);
                    bf[kk][n] = *(const short8*)&Bt[(rbase + xl * 8 + slot) * 8];
                }
#pragma unroll
            for (int kk = 0; kk < 2; ++kk)
#pragma unroll
                for (int m = 0; m < 2; ++m)
#pragma unroll
                    for (int n = 0; n < 2; ++n)
                        acc[m][n] = __builtin_amdgcn_mfma_f32_16x16x32_bf16(
                            wreg[tap][kk][m], bf[kk][n], acc[m][n], 0, 0, 0);
        }

        if (!EPI) {
#pragma unroll
            for (int m = 0; m < 2; ++m) {
                int ocb = wr * 32 + m * 16 + l4 * 4;
#pragma unroll
                for (int n = 0; n < 2; ++n) {
                    int x = x0c + wc * 32 + n * 16 + l15;
                    if (x >= Hout) continue;
                    size_t off = (((size_t)b * Hout + y) * Hout + x) * 64 + ocb;
                    short4v pk;
#pragma unroll
                    for (int r = 0; r < 4; ++r)
                        pk[r] = f2bf(fmaxf(acc[m][n][r] + bias[ocb + r], 0.f));
                    *(short4v*)(outbf + off) = pk;
                }
            }
        } else {
#pragma unroll
            for (int n = 0; n < 2; ++n) {
                const int xn = x0c + wc * 32 + n * 16 + l15;
                const int xg = (xn < 374) ? xn : 373;
                const int gbase = i * 72 + (xg - x0c);
                float mx = -1e30f;
#pragma unroll
                for (int m = 0; m < 2; ++m)
#pragma unroll
                    for (int r = 0; r < 4; ++r)
                        mx = fmaxf(mx, acc[m][n][r] + bv[m][r]);
                mx = fmaxf(mx, __shfl_xor(mx, 16));
                mx = fmaxf(mx, __shfl_xor(mx, 32));
                float den = 0.f, num = 0.f;
#pragma unroll
                for (int m = 0; m < 2; ++m)
#pragma unroll
                    for (int r = 0; r < 4; ++r) {
                        float e = exp2f(acc[m][n][r] + bv[m][r] - mx);
                        den += e;
                        num = fmaf(e, smP[gbase + goff[m][r]], num);
                    }
                den += __shfl_xor(den, 16);  den += __shfl_xor(den, 32);
                num += __shfl_xor(num, 16);  num += __shfl_xor(num, 32);
                if (l4 == 0) {
                    int p = wc * 32 + n * 16 + l15;
                    smM[wr][p] = mx;
                    smD[wr][p] = den;
                    smN[wr][p] = num;
                }
            }
            // cross-wave combine: LDS-only barrier (no vmcnt drain)
            asm volatile("s_waitcnt lgkmcnt(0)\n\ts_barrier" ::: "memory");
            if (tid < 64) {
                int p = tid, x = x0c + p;
                if (x < 374) {
                    float m0 = smM[0][p], m1 = smM[1][p];
                    float M = fmaxf(m0, m1);
                    float s0 = exp2f(m0 - M), s1 = exp2f(m1 - M);
                    float D = smD[0][p] * s0 + smD[1][p] * s1;
                    float N = smN[0][p] * s0 + smN[1][p] * s1;
                    if (z < 6) {
                        int color = (z < 3) ? 0 : 2;
                        int oy, ox;
                        switch (z) {
                            case 0: oy = 0; ox = 0; break;   // red f0
                            case 1: oy = 1; ox = 0; break;   // red f1
                            case 2: oy = 1; ox = 1; break;   // red f2
                            case 3: oy = 0; ox = 0; break;   // blue f0
                            case 4: oy = 0; ox = 1; break;   // blue f1
                            default: oy = 1; ox = 1; break;  // blue f2
                        }
                        out[(((size_t)b * 3 + color) * 748 + 2 * y + oy) * 748 + 2 * x + ox] = N / D;
                    } else {
                        size_t po = (((size_t)(z - 6) * 2 + b) * 374 + y) * 374 + x;
                        pM[po] = M; pD[po] = D; pN[po] = N;
                    }
                }
            }
        }

        // prefetch row y+5 (needed 3 iters from now)
        if (i <= cnt - 4) stage_row(y + 5);
        // counted barrier: stage of row y+3 (needed next iter) is complete
        // once <=4 vmem ops remain (the 2 newest stages).
        asm volatile("s_waitcnt vmcnt(4) lgkmcnt(0)\n\ts_barrier" ::: "memory");
    }
}

// green partial combine + raw passthrough pixels (pM in log2 domain)
__global__ __launch_bounds__(256) void rawcomb_k(
    const float* __restrict__ x0f,
    const float* __restrict__ pM, const float* __restrict__ pD,
    const float* __restrict__ pN,
    float* __restrict__ out) {
    int idx = blockIdx.x * 256 + threadIdx.x;
    if (idx >= 2 * 374 * 374) return;
    int x = idx % 374;
    int t = idx / 374;
    int y = t % 374;
    int b = t / 374;
    const float* pb = x0f + (size_t)b * 4 * 384 * 384;
    float* ob = out + (size_t)b * 3 * 748 * 748;
    float g0v = pb[(y + 5) * 384 + x + 5];
    float blv = pb[384 * 384 + (y + 5) * 384 + x + 5];
    float rrv = pb[2 * 384 * 384 + (y + 5) * 384 + x + 5];
    float g1v = pb[3 * 384 * 384 + (y + 5) * 384 + x + 5];
    ob[((size_t)0 * 748 + 2 * y) * 748 + 2 * x + 1]     = rrv;
    ob[((size_t)2 * 748 + 2 * y + 1) * 748 + 2 * x]     = blv;
    ob[((size_t)1 * 748 + 2 * y) * 748 + 2 * x]         = g0v;
    ob[((size_t)1 * 748 + 2 * y + 1) * 748 + 2 * x + 1] = g1v;
#pragma unroll
    for (int g = 0; g < 2; ++g) {
        size_t o0 = (((size_t)(g * 2 + 0) * 2 + b) * 374 + y) * 374 + x;
        size_t o1 = (((size_t)(g * 2 + 1) * 2 + b) * 374 + y) * 374 + x;
        float m0 = pM[o0], m1 = pM[o1];
        float M = fmaxf(m0, m1);
        float s0 = exp2f(m0 - M), s1 = exp2f(m1 - M);
        float val = (pN[o0] * s0 + pN[o1] * s1) / (pD[o0] * s0 + pD[o1] * s1);
        int oy = g ? 1 : 0, ox = g ? 0 : 1;
        ob[((size_t)1 * 748 + 2 * y + oy) * 748 + 2 * x + ox] = val;
    }
}

extern "C" void kernel_launch(void* const* d_in, const int* in_sizes, int n_in,
                              void* d_out, int out_size, void* d_ws, size_t ws_size,
                              hipStream_t stream) {
    const float* mosaic = (const float*)d_in[0];
    const float* W0 = (const float*)d_in[1];  const float* b0 = (const float*)d_in[2];
    const float* W1 = (const float*)d_in[3];  const float* b1 = (const float*)d_in[4];
    const float* W2 = (const float*)d_in[5];  const float* b2 = (const float*)d_in[6];
    const float* W3 = (const float*)d_in[7];  const float* b3 = (const float*)d_in[8];
    const float* W4 = (const float*)d_in[9];  const float* b4 = (const float*)d_in[10];
    float* out = (float*)d_out;

    char* ws = (char*)d_ws;
    float* x0f    = (float*)ws;  ws += 4718592;
    short* Wq1    = (short*)ws;  ws += 73728;
    short* Wq2    = (short*)ws;  ws += 73728;
    short* Wq3    = (short*)ws;  ws += 73728;
    short* Wq4p   = (short*)ws;  ws += 737280;
    float* bias4p = (float*)ws;  ws += 2560;
    short* bufA   = (short*)ws;  ws += 37356544;
    short* bufB   = (short*)ws;  ws += 36966400;
    float* pM     = (float*)ws;  ws += 4477568;
    float* pD     = (float*)ws;  ws += 4477568;
    float* pN     = (float*)ws;

    split_k<<<(2 * 4 * 384 * 384 + 255) / 256, 256, 0, stream>>>(mosaic, x0f);

    repack_k<<<(9 * 64 * 64 + 255) / 256, 256, 0, stream>>>(W1, Wq1);
    repack_k<<<(9 * 64 * 64 + 255) / 256, 256, 0, stream>>>(W2, Wq2);
    repack_k<<<(9 * 64 * 64 + 255) / 256, 256, 0, stream>>>(W3, Wq3);
    repack4_k<<<(9 * 640 * 64 + 255) / 256, 256, 0, stream>>>(W4, b4, Wq4p, bias4p);

    conv0_k<<<(2 * 382 * 382 + 255) / 256, 256, 0, stream>>>(x0f, W0, b0, bufA);

    // conv1-3: YITER=5, 76 strips, grid 76*6*2 = 912 (%8==0, 1.8 blocks/CU)
    convp_k<0><<<912, 256, 0, stream>>>(bufA, 382, 380, 5, 76, Wq1, 64, b1,
                                        bufB, nullptr, nullptr, nullptr, nullptr, nullptr);
    convp_k<0><<<912, 256, 0, stream>>>(bufB, 380, 378, 5, 76, Wq2, 64, b2,
                                        bufA, nullptr, nullptr, nullptr, nullptr, nullptr);
    convp_k<0><<<912, 256, 0, stream>>>(bufA, 378, 376, 5, 76, Wq3, 64, b3,
                                        bufB, nullptr, nullptr, nullptr, nullptr, nullptr);

    // conv4 + epilogue: YITER=11, 34 strips, grid 10*6*34*2 = 4080 (%8==0)
    convp_k<1><<<4080, 256, 0, stream>>>(bufB, 376, 374, 11, 34, Wq4p, 640, bias4p,
                                         nullptr, x0f, out, pM, pD, pN);

    rawcomb_k<<<(2 * 374 * 374 + 255) / 256, 256, 0, stream>>>(x0f, pM, pD, pN, out);
}

// Round 14
// 433.239 us; speedup vs baseline: 1.8954x; 1.0924x over previous
//
#include <hip/hip_runtime.h>
#include <hip/hip_bf16.h>
#include <math.h>

// ---------------------------------------------------------------------------
// BayerKP demosaic KPN. R14: R10 champion structure exact + folded-LOG2E
// weights with raw v_exp_f32 (single-instruction 2^x; R13's exp2f was the
// slow precise OCML path — reverted).
//   Lesson bank: >128 VGPR live state spills (R6,R12); VGPR pins at 128
//   (R7-R9); 3-blocks/CU LDS squeeze fails (R11); libm exp2f != native (R13).
// ---------------------------------------------------------------------------

typedef __attribute__((ext_vector_type(8))) short short8;
typedef __attribute__((ext_vector_type(4))) short short4v;
typedef __attribute__((ext_vector_type(4))) float f32x4;

static __device__ __forceinline__ short f2bf(float v) {
    __bf16 h = (__bf16)v;
    return __builtin_bit_cast(short, h);
}
// raw v_exp_f32: r = 2^x (ISA §3); input range here is always <= 0.
static __device__ __forceinline__ float exp2_hw(float x) {
    float r;
    asm("v_exp_f32 %0, %1" : "=v"(r) : "v"(x));
    return r;
}

__global__ __launch_bounds__(256) void split_k(const float* __restrict__ mosaic,
                                               float* __restrict__ x0) {
    int idx = blockIdx.x * 256 + threadIdx.x;
    const int total = 2 * 4 * 384 * 384;
    if (idx >= total) return;
    int x = idx % 384;
    int t = idx / 384;
    int y = t % 384;  t /= 384;
    int c = t % 4;
    int b = t / 4;
    int Y = 2 * y + ((c == 1 || c == 3) ? 1 : 0);
    int X = 2 * x + ((c == 2 || c == 3) ? 1 : 0);
    const float* mb = mosaic + (size_t)b * 3 * 768 * 768;
    float g = mb[Y * 768 + X] + mb[768 * 768 + Y * 768 + X] + mb[2 * 768 * 768 + Y * 768 + X];
    x0[idx] = g;
}

// repack W[64][64][3][3] f32 -> Wq[9][64][64] bf16 (conv1-3)
__global__ __launch_bounds__(256) void repack_k(const float* __restrict__ W,
                                                short* __restrict__ dst) {
    int idx = blockIdx.x * 256 + threadIdx.x;
    if (idx >= 9 * 64 * 64) return;
    int ic = idx % 64;
    int t2 = idx / 64;
    int oc = t2 % 64;
    int t  = t2 / 64;
    dst[idx] = f2bf(W[((size_t)oc * 64 + ic) * 9 + t]);
}

// conv4 repack, permuted + scaled by log2(e) (softmax uses v_exp_f32 = 2^x):
// group k = ocn/64 (10 groups), slot ql = ocn%64, orig ch = 49*k+ql (ql<49).
__global__ __launch_bounds__(256) void repack4_k(const float* __restrict__ W4,
                                                 const float* __restrict__ b4,
                                                 short* __restrict__ Wq,
                                                 float* __restrict__ bq) {
    const float LOG2E = 1.44269504088896340736f;
    int idx = blockIdx.x * 256 + threadIdx.x;
    if (idx < 9 * 640 * 64) {
        int ic  = idx % 64;
        int t2  = idx / 64;
        int ocn = t2 % 640;
        int tap = t2 / 640;
        int k  = ocn >> 6;
        int ql = ocn & 63;
        float v = (ql < 49) ? W4[((size_t)(49 * k + ql) * 64 + ic) * 9 + tap] * LOG2E : 0.f;
        Wq[idx] = f2bf(v);
    }
    if (idx < 640) {
        int k = idx >> 6, ql = idx & 63;
        bq[idx] = (ql < 49) ? b4[49 * k + ql] * LOG2E : 0.f;
    }
}

// conv0: direct f32, Cin=4, 384->382, ReLU, NHWC bf16 out
__global__ __launch_bounds__(256) void conv0_k(const float* __restrict__ x0f,
                                               const float* __restrict__ W0,
                                               const float* __restrict__ b0,
                                               short* __restrict__ out) {
    __shared__ float w[64 * 36];
    __shared__ float bb[64];
    for (int e = threadIdx.x; e < 64 * 36; e += 256) w[e] = W0[e];
    if (threadIdx.x < 64) bb[threadIdx.x] = b0[threadIdx.x];
    __syncthreads();
    int idx = blockIdx.x * 256 + threadIdx.x;
    if (idx >= 2 * 382 * 382) return;
    int x = idx % 382;
    int t = idx / 382;
    int y = t % 382;
    int b = t / 382;
    const float* base = x0f + (size_t)b * 4 * 384 * 384;
    float in[4][9];
#pragma unroll
    for (int ic = 0; ic < 4; ++ic)
#pragma unroll
        for (int ky = 0; ky < 3; ++ky)
#pragma unroll
            for (int kx = 0; kx < 3; ++kx)
                in[ic][ky * 3 + kx] = base[ic * 384 * 384 + (y + ky) * 384 + (x + kx)];
    short* op = out + (((size_t)b * 382 + y) * 382 + x) * 64;
    float accs[8];
    for (int og = 0; og < 8; ++og) {
#pragma unroll
        for (int oo = 0; oo < 8; ++oo) {
            int oc = og * 8 + oo;
            float acc = bb[oc];
            const float* wp = w + oc * 36;
#pragma unroll
            for (int ic = 0; ic < 4; ++ic)
#pragma unroll
                for (int e = 0; e < 9; ++e)
                    acc = fmaf(in[ic][e], wp[ic * 9 + e], acc);
            accs[oo] = fmaxf(acc, 0.f);
        }
        short8 pk;
#pragma unroll
        for (int oo = 0; oo < 8; ++oo) pk[oo] = f2bf(accs[oo]);
        *(short8*)(op + og * 8) = pk;
    }
}

// Persistent-weight conv, counted-vmcnt row pipeline (R10 structure).
// EPI=0: bias+ReLU+bf16 NHWC store. EPI=1: conv4 softmax groups.
template <int EPI>
__global__ __launch_bounds__(256, 2) void convp_k(
    const short* __restrict__ act,   // NHWC bf16 [2][Hin][Hin][64]
    int Hin, int Hout, int YITER, int nstrips,
    const short* __restrict__ Wq,    // [9][CoutT][64] bf16
    int CoutT,
    const float* __restrict__ bias,
    short* __restrict__ outbf,       // EPI=0
    const float* __restrict__ x0f,   // EPI=1
    float* __restrict__ out,         // EPI=1
    float* __restrict__ pM, float* __restrict__ pD, float* __restrict__ pN) {
    const int tid = threadIdx.x;
    const int wave = tid >> 6;
    const int lane = tid & 63;
    const int wr = wave >> 1, wc = wave & 1;
    const int l15 = lane & 15, l4 = lane >> 4;

    // bijective XCD swizzle (grid % 8 == 0); z,xt fastest for L2 act reuse
    const int q8 = gridDim.x >> 3;
    int L = ((int)blockIdx.x & 7) * q8 + ((int)blockIdx.x >> 3);
    int z = 0;
    if (EPI) { z = L % 10; L /= 10; }
    const int xt = L % 6; L /= 6;
    const int strip = L % nstrips;
    const int b = L / nstrips;
    const int x0c = xt * 64;
    const int y0 = strip * YITER;
    const int cnt = min(YITER, Hout - y0);
    if (cnt <= 0) return;

    __shared__ __align__(16) short Bt[8 * 528 * 8];  // 8-slot row ring
    __shared__ float smM[2][64], smD[2][64], smN[2][64];
    __shared__ float smP[17 * 72];                    // EPI plane window, f32

    auto stage_row = [&](int r) {
        const size_t rowbase = ((size_t)b * Hin + r) * (size_t)Hin;
        const int ring = (r & 7) * 528;
#pragma unroll
        for (int i = 0; i < 2; ++i) {
            int s = i * 256 + tid;
            int xl = s >> 3, sl = s & 7;
            int gx = x0c + xl; if (gx > Hin - 1) gx = Hin - 1;
            const short* src = act + (rowbase + gx) * 64 + ((sl ^ (xl & 7)) << 3);
            __builtin_amdgcn_global_load_lds(
                (const __attribute__((address_space(1))) void*)src,
                (__attribute__((address_space(3))) void*)((char*)Bt + (ring + s) * 16),
                16, 0, 0);
        }
        if (tid < 16) {
            int s = 512 + tid;
            int xl = s >> 3, sl = s & 7;
            int gx = x0c + xl; if (gx > Hin - 1) gx = Hin - 1;
            const short* src = act + (rowbase + gx) * 64 + ((sl ^ (xl & 7)) << 3);
            __builtin_amdgcn_global_load_lds(
                (const __attribute__((address_space(1))) void*)src,
                (__attribute__((address_space(3))) void*)((char*)Bt + (ring + s) * 16),
                16, 0, 0);
        }
    };

    // --- persistent weight fragments: 36 short8 per wave ---
    const int zrow = EPI ? z * 64 : 0;
    short8 wreg[9][2][2];
#pragma unroll
    for (int tap = 0; tap < 9; ++tap)
#pragma unroll
        for (int kk = 0; kk < 2; ++kk)
#pragma unroll
            for (int m = 0; m < 2; ++m)
                wreg[tap][kk][m] = *(const short8*)(Wq +
                    ((size_t)tap * CoutT + zrow + wr * 32 + m * 16 + l15) * 64
                    + kk * 32 + l4 * 8);

    // --- EPI loop-invariant precompute + LDS plane window ---
    float bv[2][4];
    int goff[2][4];
    if (EPI) {
        int pidx = (z < 3) ? 2 : (z < 6) ? 1 : ((z & 1) ? 3 : 0);
        const float* plane = x0f + ((size_t)b * 4 + pidx) * 384 * 384;
#pragma unroll
        for (int m = 0; m < 2; ++m)
#pragma unroll
            for (int r = 0; r < 4; ++r) {
                int q = wr * 32 + m * 16 + l4 * 4 + r;
                bv[m][r] = (q < 49) ? bias[z * 64 + q] : -1e30f;
                int qc = (q < 49) ? q : 48;
                goff[m][r] = (qc / 7) * 72 + (qc % 7);
            }
        // plane window rows [y0+2, y0+18], cols [x0c+2, x0c+71] (clamped)
        for (int e = tid; e < 17 * 70; e += 256) {
            int pr = e / 70, pc = e % 70;
            int gy = y0 + 2 + pr; if (gy > 383) gy = 383;
            int gx = x0c + 2 + pc; if (gx > 383) gx = 383;
            smP[pr * 72 + pc] = plane[gy * 384 + gx];
        }
    }

    // prologue: stage rows y0..y0+4 (5-deep prefetch)
    stage_row(y0);
    stage_row(y0 + 1);
    stage_row(y0 + 2);
    stage_row(y0 + 3);
    stage_row(y0 + 4);
    asm volatile("s_waitcnt vmcnt(4) lgkmcnt(0)\n\ts_barrier" ::: "memory");

    for (int i = 0; i < cnt; ++i) {
        const int y = y0 + i;

        f32x4 acc[2][2] = {};
#pragma unroll
        for (int tap = 0; tap < 9; ++tap) {
            const int ky = tap / 3, kx = tap % 3;
            const int rbase = ((y + ky) & 7) * 528;
            short8 bf[2][2];
#pragma unroll
            for (int kk = 0; kk < 2; ++kk)
#pragma unroll
                for (int n = 0; n < 2; ++n) {
                    int xl = wc * 32 + n * 16 + l15 + kx;
                    int slot = (kk * 4 + l4) ^ (xl & 7);
                    bf[kk][n] = *(const short8*)&Bt[(rbase + xl * 8 + slot) * 8];
                }
#pragma unroll
            for (int kk = 0; kk < 2; ++kk)
#pragma unroll
                for (int m = 0; m < 2; ++m)
#pragma unroll
                    for (int n = 0; n < 2; ++n)
                        acc[m][n] = __builtin_amdgcn_mfma_f32_16x16x32_bf16(
                            wreg[tap][kk][m], bf[kk][n], acc[m][n], 0, 0, 0);
        }

        if (!EPI) {
#pragma unroll
            for (int m = 0; m < 2; ++m) {
                int ocb = wr * 32 + m * 16 + l4 * 4;
#pragma unroll
                for (int n = 0; n < 2; ++n) {
                    int x = x0c + wc * 32 + n * 16 + l15;
                    if (x >= Hout) continue;
                    size_t off = (((size_t)b * Hout + y) * Hout + x) * 64 + ocb;
                    short4v pk;
#pragma unroll
                    for (int r = 0; r < 4; ++r)
                        pk[r] = f2bf(fmaxf(acc[m][n][r] + bias[ocb + r], 0.f));
                    *(short4v*)(outbf + off) = pk;
                }
            }
        } else {
#pragma unroll
            for (int n = 0; n < 2; ++n) {
                const int xn = x0c + wc * 32 + n * 16 + l15;
                const int xg = (xn < 374) ? xn : 373;
                const int gbase = i * 72 + (xg - x0c);
                float mx = -1e30f;
#pragma unroll
                for (int m = 0; m < 2; ++m)
#pragma unroll
                    for (int r = 0; r < 4; ++r)
                        mx = fmaxf(mx, acc[m][n][r] + bv[m][r]);
                mx = fmaxf(mx, __shfl_xor(mx, 16));
                mx = fmaxf(mx, __shfl_xor(mx, 32));
                float den = 0.f, num = 0.f;
#pragma unroll
                for (int m = 0; m < 2; ++m)
#pragma unroll
                    for (int r = 0; r < 4; ++r) {
                        float e = exp2_hw(acc[m][n][r] + bv[m][r] - mx);
                        den += e;
                        num = fmaf(e, smP[gbase + goff[m][r]], num);
                    }
                den += __shfl_xor(den, 16);  den += __shfl_xor(den, 32);
                num += __shfl_xor(num, 16);  num += __shfl_xor(num, 32);
                if (l4 == 0) {
                    int p = wc * 32 + n * 16 + l15;
                    smM[wr][p] = mx;
                    smD[wr][p] = den;
                    smN[wr][p] = num;
                }
            }
            // cross-wave combine: LDS-only barrier (no vmcnt drain)
            asm volatile("s_waitcnt lgkmcnt(0)\n\ts_barrier" ::: "memory");
            if (tid < 64) {
                int p = tid, x = x0c + p;
                if (x < 374) {
                    float m0 = smM[0][p], m1 = smM[1][p];
                    float M = fmaxf(m0, m1);
                    float s0 = exp2_hw(m0 - M), s1 = exp2_hw(m1 - M);
                    float D = smD[0][p] * s0 + smD[1][p] * s1;
                    float N = smN[0][p] * s0 + smN[1][p] * s1;
                    if (z < 6) {
                        int color = (z < 3) ? 0 : 2;
                        int oy, ox;
                        switch (z) {
                            case 0: oy = 0; ox = 0; break;   // red f0
                            case 1: oy = 1; ox = 0; break;   // red f1
                            case 2: oy = 1; ox = 1; break;   // red f2
                            case 3: oy = 0; ox = 0; break;   // blue f0
                            case 4: oy = 0; ox = 1; break;   // blue f1
                            default: oy = 1; ox = 1; break;  // blue f2
                        }
                        out[(((size_t)b * 3 + color) * 748 + 2 * y + oy) * 748 + 2 * x + ox] = N / D;
                    } else {
                        size_t po = (((size_t)(z - 6) * 2 + b) * 374 + y) * 374 + x;
                        pM[po] = M; pD[po] = D; pN[po] = N;
                    }
                }
            }
        }

        // prefetch row y+5 (needed 3 iters from now)
        if (i <= cnt - 4) stage_row(y + 5);
        // counted barrier: stage of row y+3 (needed next iter) is complete
        // once <=4 vmem ops remain (the 2 newest stages).
        asm volatile("s_waitcnt vmcnt(4) lgkmcnt(0)\n\ts_barrier" ::: "memory");
    }
}

// green partial combine + raw passthrough pixels (pM in log2 domain)
__global__ __launch_bounds__(256) void rawcomb_k(
    const float* __restrict__ x0f,
    const float* __restrict__ pM, const float* __restrict__ pD,
    const float* __restrict__ pN,
    float* __restrict__ out) {
    int idx = blockIdx.x * 256 + threadIdx.x;
    if (idx >= 2 * 374 * 374) return;
    int x = idx % 374;
    int t = idx / 374;
    int y = t % 374;
    int b = t / 374;
    const float* pb = x0f + (size_t)b * 4 * 384 * 384;
    float* ob = out + (size_t)b * 3 * 748 * 748;
    float g0v = pb[(y + 5) * 384 + x + 5];
    float blv = pb[384 * 384 + (y + 5) * 384 + x + 5];
    float rrv = pb[2 * 384 * 384 + (y + 5) * 384 + x + 5];
    float g1v = pb[3 * 384 * 384 + (y + 5) * 384 + x + 5];
    ob[((size_t)0 * 748 + 2 * y) * 748 + 2 * x + 1]     = rrv;
    ob[((size_t)2 * 748 + 2 * y + 1) * 748 + 2 * x]     = blv;
    ob[((size_t)1 * 748 + 2 * y) * 748 + 2 * x]         = g0v;
    ob[((size_t)1 * 748 + 2 * y + 1) * 748 + 2 * x + 1] = g1v;
#pragma unroll
    for (int g = 0; g < 2; ++g) {
        size_t o0 = (((size_t)(g * 2 + 0) * 2 + b) * 374 + y) * 374 + x;
        size_t o1 = (((size_t)(g * 2 + 1) * 2 + b) * 374 + y) * 374 + x;
        float m0 = pM[o0], m1 = pM[o1];
        float M = fmaxf(m0, m1);
        float d0 = m0 - M, d1 = m1 - M;
        float s0, s1;
        asm("v_exp_f32 %0, %1" : "=v"(s0) : "v"(d0));
        asm("v_exp_f32 %0, %1" : "=v"(s1) : "v"(d1));
        float val = (pN[o0] * s0 + pN[o1] * s1) / (pD[o0] * s0 + pD[o1] * s1);
        int oy = g ? 1 : 0, ox = g ? 0 : 1;
        ob[((size_t)1 * 748 + 2 * y + oy) * 748 + 2 * x + ox] = val;
    }
}

extern "C" void kernel_launch(void* const* d_in, const int* in_sizes, int n_in,
                              void* d_out, int out_size, void* d_ws, size_t ws_size,
                              hipStream_t stream) {
    const float* mosaic = (const float*)d_in[0];
    const float* W0 = (const float*)d_in[1];  const float* b0 = (const float*)d_in[2];
    const float* W1 = (const float*)d_in[3];  const float* b1 = (const float*)d_in[4];
    const float* W2 = (const float*)d_in[5];  const float* b2 = (const float*)d_in[6];
    const float* W3 = (const float*)d_in[7];  const float* b3 = (const float*)d_in[8];
    const float* W4 = (const float*)d_in[9];  const float* b4 = (const float*)d_in[10];
    float* out = (float*)d_out;

    char* ws = (char*)d_ws;
    float* x0f    = (float*)ws;  ws += 4718592;
    short* Wq1    = (short*)ws;  ws += 73728;
    short* Wq2    = (short*)ws;  ws += 73728;
    short* Wq3    = (short*)ws;  ws += 73728;
    short* Wq4p   = (short*)ws;  ws += 737280;
    float* bias4p = (float*)ws;  ws += 2560;
    short* bufA   = (short*)ws;  ws += 37356544;
    short* bufB   = (short*)ws;  ws += 36966400;
    float* pM     = (float*)ws;  ws += 4477568;
    float* pD     = (float*)ws;  ws += 4477568;
    float* pN     = (float*)ws;

    split_k<<<(2 * 4 * 384 * 384 + 255) / 256, 256, 0, stream>>>(mosaic, x0f);

    repack_k<<<(9 * 64 * 64 + 255) / 256, 256, 0, stream>>>(W1, Wq1);
    repack_k<<<(9 * 64 * 64 + 255) / 256, 256, 0, stream>>>(W2, Wq2);
    repack_k<<<(9 * 64 * 64 + 255) / 256, 256, 0, stream>>>(W3, Wq3);
    repack4_k<<<(9 * 640 * 64 + 255) / 256, 256, 0, stream>>>(W4, b4, Wq4p, bias4p);

    conv0_k<<<(2 * 382 * 382 + 255) / 256, 256, 0, stream>>>(x0f, W0, b0, bufA);

    // conv1-3: YITER=10, 38 strips, grid 38*6*2 = 456 (%8==0) — R10 exact
    convp_k<0><<<456, 256, 0, stream>>>(bufA, 382, 380, 10, 38, Wq1, 64, b1,
                                        bufB, nullptr, nullptr, nullptr, nullptr, nullptr);
    convp_k<0><<<456, 256, 0, stream>>>(bufB, 380, 378, 10, 38, Wq2, 64, b2,
                                        bufA, nullptr, nullptr, nullptr, nullptr, nullptr);
    convp_k<0><<<456, 256, 0, stream>>>(bufA, 378, 376, 10, 38, Wq3, 64, b3,
                                        bufB, nullptr, nullptr, nullptr, nullptr, nullptr);

    // conv4 + epilogue: YITER=11, 34 strips, grid 10*6*34*2 = 4080 (%8==0)
    convp_k<1><<<4080, 256, 0, stream>>>(bufB, 376, 374, 11, 34, Wq4p, 640, bias4p,
                                         nullptr, x0f, out, pM, pD, pN);

    rawcomb_k<<<(2 * 374 * 374 + 255) / 256, 256, 0, stream>>>(x0f, pM, pD, pN, out);
}

// Round 16
// 431.969 us; speedup vs baseline: 1.9010x; 1.0029x over previous
//
#include <hip/hip_runtime.h>
#include <hip/hip_bf16.h>
#include <math.h>

// ---------------------------------------------------------------------------
// BayerKP demosaic KPN. R16: exact restore of the R14 champion (433us).
//   - R10 pipeline: 8-slot LDS row ring, 5-deep prefetch, counted
//     s_waitcnt vmcnt(4) + raw s_barrier, LDS plane window for gathers,
//     lgkm-only mid barrier.
//   - LOG2E folded into W4/b4; softmax exp via raw v_exp_f32 (2^x) WITH the
//     max pass (R15 proved removing it breaks accuracy).
//   Lesson bank: >128 VGPR live state spills (R6,R12); VGPR pins at 128
//   (R7-R9); occupancy levers fail (R11); libm exp2f != native (R13);
//   softmax max-pass is load-bearing (R15).
// ---------------------------------------------------------------------------

typedef __attribute__((ext_vector_type(8))) short short8;
typedef __attribute__((ext_vector_type(4))) short short4v;
typedef __attribute__((ext_vector_type(4))) float f32x4;

static __device__ __forceinline__ short f2bf(float v) {
    __bf16 h = (__bf16)v;
    return __builtin_bit_cast(short, h);
}
// raw v_exp_f32: r = 2^x (ISA §3); input range here is always <= 0.
static __device__ __forceinline__ float exp2_hw(float x) {
    float r;
    asm("v_exp_f32 %0, %1" : "=v"(r) : "v"(x));
    return r;
}

__global__ __launch_bounds__(256) void split_k(const float* __restrict__ mosaic,
                                               float* __restrict__ x0) {
    int idx = blockIdx.x * 256 + threadIdx.x;
    const int total = 2 * 4 * 384 * 384;
    if (idx >= total) return;
    int x = idx % 384;
    int t = idx / 384;
    int y = t % 384;  t /= 384;
    int c = t % 4;
    int b = t / 4;
    int Y = 2 * y + ((c == 1 || c == 3) ? 1 : 0);
    int X = 2 * x + ((c == 2 || c == 3) ? 1 : 0);
    const float* mb = mosaic + (size_t)b * 3 * 768 * 768;
    float g = mb[Y * 768 + X] + mb[768 * 768 + Y * 768 + X] + mb[2 * 768 * 768 + Y * 768 + X];
    x0[idx] = g;
}

// repack W[64][64][3][3] f32 -> Wq[9][64][64] bf16 (conv1-3)
__global__ __launch_bounds__(256) void repack_k(const float* __restrict__ W,
                                                short* __restrict__ dst) {
    int idx = blockIdx.x * 256 + threadIdx.x;
    if (idx >= 9 * 64 * 64) return;
    int ic = idx % 64;
    int t2 = idx / 64;
    int oc = t2 % 64;
    int t  = t2 / 64;
    dst[idx] = f2bf(W[((size_t)oc * 64 + ic) * 9 + t]);
}

// conv4 repack, permuted + scaled by log2(e) (softmax uses v_exp_f32 = 2^x):
// group k = ocn/64 (10 groups), slot ql = ocn%64, orig ch = 49*k+ql (ql<49).
__global__ __launch_bounds__(256) void repack4_k(const float* __restrict__ W4,
                                                 const float* __restrict__ b4,
                                                 short* __restrict__ Wq,
                                                 float* __restrict__ bq) {
    const float LOG2E = 1.44269504088896340736f;
    int idx = blockIdx.x * 256 + threadIdx.x;
    if (idx < 9 * 640 * 64) {
        int ic  = idx % 64;
        int t2  = idx / 64;
        int ocn = t2 % 640;
        int tap = t2 / 640;
        int k  = ocn >> 6;
        int ql = ocn & 63;
        float v = (ql < 49) ? W4[((size_t)(49 * k + ql) * 64 + ic) * 9 + tap] * LOG2E : 0.f;
        Wq[idx] = f2bf(v);
    }
    if (idx < 640) {
        int k = idx >> 6, ql = idx & 63;
        bq[idx] = (ql < 49) ? b4[49 * k + ql] * LOG2E : 0.f;
    }
}

// conv0: direct f32, Cin=4, 384->382, ReLU, NHWC bf16 out
__global__ __launch_bounds__(256) void conv0_k(const float* __restrict__ x0f,
                                               const float* __restrict__ W0,
                                               const float* __restrict__ b0,
                                               short* __restrict__ out) {
    __shared__ float w[64 * 36];
    __shared__ float bb[64];
    for (int e = threadIdx.x; e < 64 * 36; e += 256) w[e] = W0[e];
    if (threadIdx.x < 64) bb[threadIdx.x] = b0[threadIdx.x];
    __syncthreads();
    int idx = blockIdx.x * 256 + threadIdx.x;
    if (idx >= 2 * 382 * 382) return;
    int x = idx % 382;
    int t = idx / 382;
    int y = t % 382;
    int b = t / 382;
    const float* base = x0f + (size_t)b * 4 * 384 * 384;
    float in[4][9];
#pragma unroll
    for (int ic = 0; ic < 4; ++ic)
#pragma unroll
        for (int ky = 0; ky < 3; ++ky)
#pragma unroll
            for (int kx = 0; kx < 3; ++kx)
                in[ic][ky * 3 + kx] = base[ic * 384 * 384 + (y + ky) * 384 + (x + kx)];
    short* op = out + (((size_t)b * 382 + y) * 382 + x) * 64;
    float accs[8];
    for (int og = 0; og < 8; ++og) {
#pragma unroll
        for (int oo = 0; oo < 8; ++oo) {
            int oc = og * 8 + oo;
            float acc = bb[oc];
            const float* wp = w + oc * 36;
#pragma unroll
            for (int ic = 0; ic < 4; ++ic)
#pragma unroll
                for (int e = 0; e < 9; ++e)
                    acc = fmaf(in[ic][e], wp[ic * 9 + e], acc);
            accs[oo] = fmaxf(acc, 0.f);
        }
        short8 pk;
#pragma unroll
        for (int oo = 0; oo < 8; ++oo) pk[oo] = f2bf(accs[oo]);
        *(short8*)(op + og * 8) = pk;
    }
}

// Persistent-weight conv, counted-vmcnt row pipeline (R10 structure).
// EPI=0: bias+ReLU+bf16 NHWC store. EPI=1: conv4 softmax groups.
template <int EPI>
__global__ __launch_bounds__(256, 2) void convp_k(
    const short* __restrict__ act,   // NHWC bf16 [2][Hin][Hin][64]
    int Hin, int Hout, int YITER, int nstrips,
    const short* __restrict__ Wq,    // [9][CoutT][64] bf16
    int CoutT,
    const float* __restrict__ bias,
    short* __restrict__ outbf,       // EPI=0
    const float* __restrict__ x0f,   // EPI=1
    float* __restrict__ out,         // EPI=1
    float* __restrict__ pM, float* __restrict__ pD, float* __restrict__ pN) {
    const int tid = threadIdx.x;
    const int wave = tid >> 6;
    const int lane = tid & 63;
    const int wr = wave >> 1, wc = wave & 1;
    const int l15 = lane & 15, l4 = lane >> 4;

    // bijective XCD swizzle (grid % 8 == 0); z,xt fastest for L2 act reuse
    const int q8 = gridDim.x >> 3;
    int L = ((int)blockIdx.x & 7) * q8 + ((int)blockIdx.x >> 3);
    int z = 0;
    if (EPI) { z = L % 10; L /= 10; }
    const int xt = L % 6; L /= 6;
    const int strip = L % nstrips;
    const int b = L / nstrips;
    const int x0c = xt * 64;
    const int y0 = strip * YITER;
    const int cnt = min(YITER, Hout - y0);
    if (cnt <= 0) return;

    __shared__ __align__(16) short Bt[8 * 528 * 8];  // 8-slot row ring
    __shared__ float smM[2][64], smD[2][64], smN[2][64];
    __shared__ float smP[17 * 72];                    // EPI plane window, f32

    auto stage_row = [&](int r) {
        const size_t rowbase = ((size_t)b * Hin + r) * (size_t)Hin;
        const int ring = (r & 7) * 528;
#pragma unroll
        for (int i = 0; i < 2; ++i) {
            int s = i * 256 + tid;
            int xl = s >> 3, sl = s & 7;
            int gx = x0c + xl; if (gx > Hin - 1) gx = Hin - 1;
            const short* src = act + (rowbase + gx) * 64 + ((sl ^ (xl & 7)) << 3);
            __builtin_amdgcn_global_load_lds(
                (const __attribute__((address_space(1))) void*)src,
                (__attribute__((address_space(3))) void*)((char*)Bt + (ring + s) * 16),
                16, 0, 0);
        }
        if (tid < 16) {
            int s = 512 + tid;
            int xl = s >> 3, sl = s & 7;
            int gx = x0c + xl; if (gx > Hin - 1) gx = Hin - 1;
            const short* src = act + (rowbase + gx) * 64 + ((sl ^ (xl & 7)) << 3);
            __builtin_amdgcn_global_load_lds(
                (const __attribute__((address_space(1))) void*)src,
                (__attribute__((address_space(3))) void*)((char*)Bt + (ring + s) * 16),
                16, 0, 0);
        }
    };

    // --- persistent weight fragments: 36 short8 per wave ---
    const int zrow = EPI ? z * 64 : 0;
    short8 wreg[9][2][2];
#pragma unroll
    for (int tap = 0; tap < 9; ++tap)
#pragma unroll
        for (int kk = 0; kk < 2; ++kk)
#pragma unroll
            for (int m = 0; m < 2; ++m)
                wreg[tap][kk][m] = *(const short8*)(Wq +
                    ((size_t)tap * CoutT + zrow + wr * 32 + m * 16 + l15) * 64
                    + kk * 32 + l4 * 8);

    // --- EPI loop-invariant precompute + LDS plane window ---
    float bv[2][4];
    int goff[2][4];
    if (EPI) {
        int pidx = (z < 3) ? 2 : (z < 6) ? 1 : ((z & 1) ? 3 : 0);
        const float* plane = x0f + ((size_t)b * 4 + pidx) * 384 * 384;
#pragma unroll
        for (int m = 0; m < 2; ++m)
#pragma unroll
            for (int r = 0; r < 4; ++r) {
                int q = wr * 32 + m * 16 + l4 * 4 + r;
                bv[m][r] = (q < 49) ? bias[z * 64 + q] : -1e30f;
                int qc = (q < 49) ? q : 48;
                goff[m][r] = (qc / 7) * 72 + (qc % 7);
            }
        // plane window rows [y0+2, y0+18], cols [x0c+2, x0c+71] (clamped)
        for (int e = tid; e < 17 * 70; e += 256) {
            int pr = e / 70, pc = e % 70;
            int gy = y0 + 2 + pr; if (gy > 383) gy = 383;
            int gx = x0c + 2 + pc; if (gx > 383) gx = 383;
            smP[pr * 72 + pc] = plane[gy * 384 + gx];
        }
    }

    // prologue: stage rows y0..y0+4 (5-deep prefetch)
    stage_row(y0);
    stage_row(y0 + 1);
    stage_row(y0 + 2);
    stage_row(y0 + 3);
    stage_row(y0 + 4);
    asm volatile("s_waitcnt vmcnt(4) lgkmcnt(0)\n\ts_barrier" ::: "memory");

    for (int i = 0; i < cnt; ++i) {
        const int y = y0 + i;

        f32x4 acc[2][2] = {};
#pragma unroll
        for (int tap = 0; tap < 9; ++tap) {
            const int ky = tap / 3, kx = tap % 3;
            const int rbase = ((y + ky) & 7) * 528;
            short8 bf[2][2];
#pragma unroll
            for (int kk = 0; kk < 2; ++kk)
#pragma unroll
                for (int n = 0; n < 2; ++n) {
                    int xl = wc * 32 + n * 16 + l15 + kx;
                    int slot = (kk * 4 + l4) ^ (xl & 7);
                    bf[kk][n] = *(const short8*)&Bt[(rbase + xl * 8 + slot) * 8];
                }
#pragma unroll
            for (int kk = 0; kk < 2; ++kk)
#pragma unroll
                for (int m = 0; m < 2; ++m)
#pragma unroll
                    for (int n = 0; n < 2; ++n)
                        acc[m][n] = __builtin_amdgcn_mfma_f32_16x16x32_bf16(
                            wreg[tap][kk][m], bf[kk][n], acc[m][n], 0, 0, 0);
        }

        if (!EPI) {
#pragma unroll
            for (int m = 0; m < 2; ++m) {
                int ocb = wr * 32 + m * 16 + l4 * 4;
#pragma unroll
                for (int n = 0; n < 2; ++n) {
                    int x = x0c + wc * 32 + n * 16 + l15;
                    if (x >= Hout) continue;
                    size_t off = (((size_t)b * Hout + y) * Hout + x) * 64 + ocb;
                    short4v pk;
#pragma unroll
                    for (int r = 0; r < 4; ++r)
                        pk[r] = f2bf(fmaxf(acc[m][n][r] + bias[ocb + r], 0.f));
                    *(short4v*)(outbf + off) = pk;
                }
            }
        } else {
#pragma unroll
            for (int n = 0; n < 2; ++n) {
                const int xn = x0c + wc * 32 + n * 16 + l15;
                const int xg = (xn < 374) ? xn : 373;
                const int gbase = i * 72 + (xg - x0c);
                float mx = -1e30f;
#pragma unroll
                for (int m = 0; m < 2; ++m)
#pragma unroll
                    for (int r = 0; r < 4; ++r)
                        mx = fmaxf(mx, acc[m][n][r] + bv[m][r]);
                mx = fmaxf(mx, __shfl_xor(mx, 16));
                mx = fmaxf(mx, __shfl_xor(mx, 32));
                float den = 0.f, num = 0.f;
#pragma unroll
                for (int m = 0; m < 2; ++m)
#pragma unroll
                    for (int r = 0; r < 4; ++r) {
                        float e = exp2_hw(acc[m][n][r] + bv[m][r] - mx);
                        den += e;
                        num = fmaf(e, smP[gbase + goff[m][r]], num);
                    }
                den += __shfl_xor(den, 16);  den += __shfl_xor(den, 32);
                num += __shfl_xor(num, 16);  num += __shfl_xor(num, 32);
                if (l4 == 0) {
                    int p = wc * 32 + n * 16 + l15;
                    smM[wr][p] = mx;
                    smD[wr][p] = den;
                    smN[wr][p] = num;
                }
            }
            // cross-wave combine: LDS-only barrier (no vmcnt drain)
            asm volatile("s_waitcnt lgkmcnt(0)\n\ts_barrier" ::: "memory");
            if (tid < 64) {
                int p = tid, x = x0c + p;
                if (x < 374) {
                    float m0 = smM[0][p], m1 = smM[1][p];
                    float M = fmaxf(m0, m1);
                    float s0 = exp2_hw(m0 - M), s1 = exp2_hw(m1 - M);
                    float D = smD[0][p] * s0 + smD[1][p] * s1;
                    float N = smN[0][p] * s0 + smN[1][p] * s1;
                    if (z < 6) {
                        int color = (z < 3) ? 0 : 2;
                        int oy, ox;
                        switch (z) {
                            case 0: oy = 0; ox = 0; break;   // red f0
                            case 1: oy = 1; ox = 0; break;   // red f1
                            case 2: oy = 1; ox = 1; break;   // red f2
                            case 3: oy = 0; ox = 0; break;   // blue f0
                            case 4: oy = 0; ox = 1; break;   // blue f1
                            default: oy = 1; ox = 1; break;  // blue f2
                        }
                        out[(((size_t)b * 3 + color) * 748 + 2 * y + oy) * 748 + 2 * x + ox] = N / D;
                    } else {
                        size_t po = (((size_t)(z - 6) * 2 + b) * 374 + y) * 374 + x;
                        pM[po] = M; pD[po] = D; pN[po] = N;
                    }
                }
            }
        }

        // prefetch row y+5 (needed 3 iters from now)
        if (i <= cnt - 4) stage_row(y + 5);
        // counted barrier: stage of row y+3 (needed next iter) is complete
        // once <=4 vmem ops remain (the 2 newest stages).
        asm volatile("s_waitcnt vmcnt(4) lgkmcnt(0)\n\ts_barrier" ::: "memory");
    }
}

// green partial combine + raw passthrough pixels (pM in log2 domain)
__global__ __launch_bounds__(256) void rawcomb_k(
    const float* __restrict__ x0f,
    const float* __restrict__ pM, const float* __restrict__ pD,
    const float* __restrict__ pN,
    float* __restrict__ out) {
    int idx = blockIdx.x * 256 + threadIdx.x;
    if (idx >= 2 * 374 * 374) return;
    int x = idx % 374;
    int t = idx / 374;
    int y = t % 374;
    int b = t / 374;
    const float* pb = x0f + (size_t)b * 4 * 384 * 384;
    float* ob = out + (size_t)b * 3 * 748 * 748;
    float g0v = pb[(y + 5) * 384 + x + 5];
    float blv = pb[384 * 384 + (y + 5) * 384 + x + 5];
    float rrv = pb[2 * 384 * 384 + (y + 5) * 384 + x + 5];
    float g1v = pb[3 * 384 * 384 + (y + 5) * 384 + x + 5];
    ob[((size_t)0 * 748 + 2 * y) * 748 + 2 * x + 1]     = rrv;
    ob[((size_t)2 * 748 + 2 * y + 1) * 748 + 2 * x]     = blv;
    ob[((size_t)1 * 748 + 2 * y) * 748 + 2 * x]         = g0v;
    ob[((size_t)1 * 748 + 2 * y + 1) * 748 + 2 * x + 1] = g1v;
#pragma unroll
    for (int g = 0; g < 2; ++g) {
        size_t o0 = (((size_t)(g * 2 + 0) * 2 + b) * 374 + y) * 374 + x;
        size_t o1 = (((size_t)(g * 2 + 1) * 2 + b) * 374 + y) * 374 + x;
        float m0 = pM[o0], m1 = pM[o1];
        float M = fmaxf(m0, m1);
        float d0 = m0 - M, d1 = m1 - M;
        float s0, s1;
        asm("v_exp_f32 %0, %1" : "=v"(s0) : "v"(d0));
        asm("v_exp_f32 %0, %1" : "=v"(s1) : "v"(d1));
        float val = (pN[o0] * s0 + pN[o1] * s1) / (pD[o0] * s0 + pD[o1] * s1);
        int oy = g ? 1 : 0, ox = g ? 0 : 1;
        ob[((size_t)1 * 748 + 2 * y + oy) * 748 + 2 * x + ox] = val;
    }
}

extern "C" void kernel_launch(void* const* d_in, const int* in_sizes, int n_in,
                              void* d_out, int out_size, void* d_ws, size_t ws_size,
                              hipStream_t stream) {
    const float* mosaic = (const float*)d_in[0];
    const float* W0 = (const float*)d_in[1];  const float* b0 = (const float*)d_in[2];
    const float* W1 = (const float*)d_in[3];  const float* b1 = (const float*)d_in[4];
    const float* W2 = (const float*)d_in[5];  const float* b2 = (const float*)d_in[6];
    const float* W3 = (const float*)d_in[7];  const float* b3 = (const float*)d_in[8];
    const float* W4 = (const float*)d_in[9];  const float* b4 = (const float*)d_in[10];
    float* out = (float*)d_out;

    char* ws = (char*)d_ws;
    float* x0f    = (float*)ws;  ws += 4718592;
    short* Wq1    = (short*)ws;  ws += 73728;
    short* Wq2    = (short*)ws;  ws += 73728;
    short* Wq3    = (short*)ws;  ws += 73728;
    short* Wq4p   = (short*)ws;  ws += 737280;
    float* bias4p = (float*)ws;  ws += 2560;
    short* bufA   = (short*)ws;  ws += 37356544;
    short* bufB   = (short*)ws;  ws += 36966400;
    float* pM     = (float*)ws;  ws += 4477568;
    float* pD     = (float*)ws;  ws += 4477568;
    float* pN     = (float*)ws;

    split_k<<<(2 * 4 * 384 * 384 + 255) / 256, 256, 0, stream>>>(mosaic, x0f);

    repack_k<<<(9 * 64 * 64 + 255) / 256, 256, 0, stream>>>(W1, Wq1);
    repack_k<<<(9 * 64 * 64 + 255) / 256, 256, 0, stream>>>(W2, Wq2);
    repack_k<<<(9 * 64 * 64 + 255) / 256, 256, 0, stream>>>(W3, Wq3);
    repack4_k<<<(9 * 640 * 64 + 255) / 256, 256, 0, stream>>>(W4, b4, Wq4p, bias4p);

    conv0_k<<<(2 * 382 * 382 + 255) / 256, 256, 0, stream>>>(x0f, W0, b0, bufA);

    // conv1-3: YITER=10, 38 strips, grid 38*6*2 = 456 (%8==0) — R10 exact
    convp_k<0><<<456, 256, 0, stream>>>(bufA, 382, 380, 10, 38, Wq1, 64, b1,
                                        bufB, nullptr, nullptr, nullptr, nullptr, nullptr);
    convp_k<0><<<456, 256, 0, stream>>>(bufB, 380, 378, 10, 38, Wq2, 64, b2,
                                        bufA, nullptr, nullptr, nullptr, nullptr, nullptr);
    convp_k<0><<<456, 256, 0, stream>>>(bufA, 378, 376, 10, 38, Wq3, 64, b3,
                                        bufB, nullptr, nullptr, nullptr, nullptr, nullptr);

    // conv4 + epilogue: YITER=11, 34 strips, grid 10*6*34*2 = 4080 (%8==0)
    convp_k<1><<<4080, 256, 0, stream>>>(bufB, 376, 374, 11, 34, Wq4p, 640, bias4p,
                                         nullptr, x0f, out, pM, pD, pN);

    rawcomb_k<<<(2 * 374 * 374 + 255) / 256, 256, 0, stream>>>(x0f, pM, pD, pN, out);
}